// Round 13
// baseline (1089.104 us; speedup 1.0000x reference)
//
#include <hip/hip_runtime.h>

// LSTM cell, B=8192, IN=H=2048, fp32 in/out.
// Round 13: A direct-to-register (no LDS for A) — kills 2/3 of LDS traffic.
// LDS = B only: 2 buf x [2 kk][256 r][32 K] bf16 = 64 KiB, proven r2-r9
// zero-conflict layout (64B rows, slot ^= (row>>1)&3; inverse on source).
// 16x16x32 MFMA, 8 waves, wave tile 128x64. Per tile: 8 B ds_reads + 16 A
// global_load_dwordx4 (issued one phase ahead, disjoint register lifetimes)
// + 4 B-GLDS stages. Gates: vmcnt(20)@ph1, vmcnt(14)@ph3 (exact per fixed
// per-phase vmem order). Epilogue: r8 shfl-free (gate == fragment n).
// Pack: X2 bf16 [8192][4096] = [x|h];  W3 bf16 [8192][4096] with row
//   j = (hc>>4)*64 + gate*16 + (hc&15).

typedef __attribute__((ext_vector_type(8))) short short8;
typedef __attribute__((ext_vector_type(8))) __bf16 bf16x8;
typedef __attribute__((ext_vector_type(4))) float f32x4;

#define GLDS(gp, lp)                                                        \
  __builtin_amdgcn_global_load_lds(                                         \
      (const __attribute__((address_space(1))) void*)(gp),                  \
      (__attribute__((address_space(3))) void*)(lp), 16, 0, 0)

__device__ __forceinline__ unsigned short f2bf(float f) {
  unsigned u = __builtin_bit_cast(unsigned, f);
  u = (u + 0x7FFFu + ((u >> 16) & 1u)) >> 16;  // RNE
  return (unsigned short)u;
}

// ---- pack [x | h] -> X2 bf16 [8192][4096] ----
__global__ void pack_x_kernel(const float* __restrict__ x,
                              const float* __restrict__ h,
                              short* __restrict__ X2) {
  long tid = (long)blockIdx.x * blockDim.x + threadIdx.x;
  long flat = tid * 8;
  int row = (int)(flat >> 12);
  int k = (int)(flat & 4095);
  const float* src = (k < 2048) ? (x + (long)row * 2048 + k)
                                : (h + (long)row * 2048 + (k - 2048));
  float4 a = *(const float4*)src;
  float4 b = *(const float4*)(src + 4);
  short8 o;
  o[0] = (short)f2bf(a.x); o[1] = (short)f2bf(a.y);
  o[2] = (short)f2bf(a.z); o[3] = (short)f2bf(a.w);
  o[4] = (short)f2bf(b.x); o[5] = (short)f2bf(b.y);
  o[6] = (short)f2bf(b.z); o[7] = (short)f2bf(b.w);
  *(short8*)(X2 + flat) = o;
}

// ---- pack weights -> W3 bf16 [8192][4096]; row j: hc=(j>>6)*16+(j&15), g=(j>>4)&3 ----
__global__ void pack_w_kernel(const float* __restrict__ wxf, const float* __restrict__ wxi,
                              const float* __restrict__ wxo, const float* __restrict__ wxc,
                              const float* __restrict__ whf, const float* __restrict__ whi,
                              const float* __restrict__ who, const float* __restrict__ whc,
                              short* __restrict__ W3) {
  long tid = (long)blockIdx.x * blockDim.x + threadIdx.x;
  long flat = tid * 8;
  int j = (int)(flat >> 12);
  int k = (int)(flat & 4095);
  int hc = ((j >> 6) << 4) | (j & 15);
  int g = (j >> 4) & 3;
  const float* base;
  if (k < 2048) {
    const float* wx = (g == 0) ? wxf : (g == 1) ? wxi : (g == 2) ? wxo : wxc;
    base = wx + (long)hc * 2048 + k;
  } else {
    const float* wh = (g == 0) ? whf : (g == 1) ? whi : (g == 2) ? who : whc;
    base = wh + (long)hc * 2048 + (k - 2048);
  }
  float4 a = *(const float4*)base;
  float4 b = *(const float4*)(base + 4);
  short8 o;
  o[0] = (short)f2bf(a.x); o[1] = (short)f2bf(a.y);
  o[2] = (short)f2bf(a.z); o[3] = (short)f2bf(a.w);
  o[4] = (short)f2bf(b.x); o[5] = (short)f2bf(b.y);
  o[6] = (short)f2bf(b.z); o[7] = (short)f2bf(b.w);
  *(short8*)(W3 + flat) = o;
}

// ---- 256x256 fused GEMM (A-in-reg, B-in-LDS) + LSTM epilogue ----
__global__ __launch_bounds__(512, 2) void lstm_fused_gemm(
    const short* __restrict__ X2, const short* __restrict__ W3,
    const float* __restrict__ cin,
    const float* __restrict__ bF, const float* __restrict__ bI,
    const float* __restrict__ bO, const float* __restrict__ bC,
    float* __restrict__ hout, float* __restrict__ cout_) {
  __shared__ __align__(16) short lds[32768];  // 64 KiB: 2 buf x 32 KB (B)

  const int tid = threadIdx.x;
  const int lane = tid & 63;
  const int w = tid >> 6;        // 0..7
  const int wm = w >> 2;         // 0..1  (M half, 128 rows)
  const int wn = w & 3;          // 0..3  (N quarter, 64 cols)

  // XCD super-tile (r5-r8 proven): 32 co-resident blocks/XCD = 4 bM x 8 bN.
  const int bid = blockIdx.x;
  const int bM = (bid & 7) * 4 + ((bid >> 3) & 3);  // 0..31
  const int bN = bid >> 5;                          // 0..31

  // --- B staging geometry (r2-r9 verbatim; inverse swizzle on source) ---
  const int r0 = tid >> 2;                      // 0..127
  const int ss = (tid & 3) ^ ((r0 >> 1) & 3);   // pre-swizzled source slot
  const short* bRow0 = W3 + ((size_t)(bN * 256 + r0)) * 4096 + ss * 8;
  const short* bRow1 = bRow0 + (size_t)128 * 4096;

  // LDS buffer bb in {0,32768} bytes; region kk in {0,1} of 16 KB.
#define STAGE_B(kk, tt, bb) do {                                             \
    GLDS(bRow0 + (tt) * 64 + (kk) * 32,                                      \
         (char*)lds + (bb) + (kk) * 16384 + tid * 16);                       \
    GLDS(bRow1 + (tt) * 64 + (kk) * 32,                                      \
         (char*)lds + (bb) + (kk) * 16384 + 8192 + tid * 16);                \
  } while (0)

  // --- B ds_read geometry (forward swizzle; per-lane const) ---
  const int lr = lane & 15, hi = lane >> 4;     // hi = k-slot 0..3
  const int R0 = wn * 64 + lr;
  const int fB = (R0 >> 1) & 3;
  const int bbase = R0 * 64 + ((hi ^ fB) << 4); // + n*1024 + kk*16384 + buf

  // --- A direct-load geometry: lane reads 16B at row(m), k-slot hi ---
  const short* aBase = X2 + ((size_t)(bM * 256 + wm * 128 + lr)) * 4096 + hi * 8;
#define ALOAD(dst, mh, kk, tt)                                               \
  do {                                                                       \
    _Pragma("unroll")                                                        \
    for (int mi = 0; mi < 4; ++mi)                                           \
      dst[mi] = *(const bf16x8*)(aBase + (size_t)((mh) * 64 + mi * 16) * 4096 \
                                 + (tt) * 64 + (kk) * 32);                   \
  } while (0)

#define LDSRD(off) (*(const bf16x8*)((const char*)lds + (off)))
#define MFMA_(a, b, c) __builtin_amdgcn_mfma_f32_16x16x32_bf16((a), (b), (c), 0, 0, 0)

  f32x4 acc[8][4] = {};  // [m = mh*4+mi][n==gate]
  bf16x8 aP[4], aQ[4];   // alternating A sets (disjoint lifetimes)
  bf16x8 b0[4], b1[4];

  // --- prologue: B(t0) both halves -> buf0 (4 GLDS); A(mh0,kk0,t0) ---
  STAGE_B(0, 0, 0);
  STAGE_B(1, 0, 0);
  ALOAD(aP, 0, 0, 0);
  asm volatile("s_waitcnt vmcnt(4)" ::: "memory");   // B landed; A in flight
  __builtin_amdgcn_s_barrier();

#pragma unroll 2
  for (int t = 0; t < 64; ++t) {
    const int bo = (t & 1) * 32768;
    const int bon = bo ^ 32768;
    const int t1 = (t + 1) & 63;   // t=63 stages/loads dummy (never read; safe)

    // ---- ph0 (mh0,kk0): read b0; issue aQ=A(mh1,kk0); stage B-kk0(t+1) ----
#pragma unroll
    for (int n = 0; n < 4; ++n) b0[n] = LDSRD(bo + bbase + n * 1024);
    ALOAD(aQ, 1, 0, t);
    STAGE_B(0, t1, bon);
    __builtin_amdgcn_s_barrier();
    __builtin_amdgcn_s_setprio(1);
#pragma unroll
    for (int n = 0; n < 4; ++n)
#pragma unroll
      for (int mi = 0; mi < 4; ++mi) acc[mi][n] = MFMA_(aP[mi], b0[n], acc[mi][n]);
    __builtin_amdgcn_s_setprio(0);

    // ---- ph1 (mh1,kk0): read b1(kk1); issue aP=A(mh0,kk1); stage B-kk1(t+1);
    //      vmcnt(20) guards B-kk1(t) for ph2 reads ----
#pragma unroll
    for (int n = 0; n < 4; ++n) b1[n] = LDSRD(bo + 16384 + bbase + n * 1024);
    ALOAD(aP, 0, 1, t);
    STAGE_B(1, t1, bon);
    asm volatile("s_waitcnt vmcnt(20)" ::: "memory");
    __builtin_amdgcn_s_barrier();
    __builtin_amdgcn_s_setprio(1);
#pragma unroll
    for (int n = 0; n < 4; ++n)
#pragma unroll
      for (int mi = 0; mi < 4; ++mi) acc[4 + mi][n] = MFMA_(aQ[mi], b0[n], acc[4 + mi][n]);
    __builtin_amdgcn_s_setprio(0);

    // ---- ph2 (mh0,kk1): issue aQ=A(mh1,kk1) ----
    ALOAD(aQ, 1, 1, t);
    __builtin_amdgcn_s_barrier();
    __builtin_amdgcn_s_setprio(1);
#pragma unroll
    for (int n = 0; n < 4; ++n)
#pragma unroll
      for (int mi = 0; mi < 4; ++mi) acc[mi][n] = MFMA_(aP[mi], b1[n], acc[mi][n]);
    __builtin_amdgcn_s_setprio(0);

    // ---- ph3 (mh1,kk1): issue aP=A(mh0,kk0,t+1); vmcnt(14) guards B-kk0(t+1) ----
    ALOAD(aP, 0, 0, t1);
    asm volatile("s_waitcnt vmcnt(14)" ::: "memory");
    __builtin_amdgcn_s_barrier();
    __builtin_amdgcn_s_setprio(1);
#pragma unroll
    for (int n = 0; n < 4; ++n)
#pragma unroll
      for (int mi = 0; mi < 4; ++mi) acc[4 + mi][n] = MFMA_(aQ[mi], b1[n], acc[4 + mi][n]);
    __builtin_amdgcn_s_setprio(0);
  }

  // ---- fused LSTM epilogue (r8 verbatim: gate g == fragment n, no shfl) ----
  const int hc = bN * 64 + wn * 16 + lr;
  const float vbf = bF[hc], vbi = bI[hc], vbo = bO[hc], vbc = bC[hc];
#pragma unroll
  for (int m = 0; m < 8; ++m) {
    const int rbase = bM * 256 + wm * 128 + m * 16 + hi * 4;
#pragma unroll
    for (int v = 0; v < 4; ++v) {
      const size_t idx = (size_t)(rbase + v) * 2048 + hc;
      float gf = acc[m][0][v] + vbf;
      float gi = acc[m][1][v] + vbi;
      float go = acc[m][2][v] + vbo;
      float gc = acc[m][3][v] + vbc;
      float fg = 1.f / (1.f + __expf(-gf));
      float ig = 1.f / (1.f + __expf(-gi));
      float og = 1.f / (1.f + __expf(-go));
      float ct = 2.f / (1.f + __expf(-2.f * gc)) - 1.f;
      float cn = fg * cin[idx] + ig * ct;
      float hn = og * (2.f / (1.f + __expf(-2.f * cn)) - 1.f);
      hout[idx] = hn;
      cout_[idx] = cn;
    }
  }
}

extern "C" void kernel_launch(void* const* d_in, const int* in_sizes, int n_in,
                              void* d_out, int out_size, void* d_ws, size_t ws_size,
                              hipStream_t stream) {
  const float* x    = (const float*)d_in[0];
  const float* h    = (const float*)d_in[1];
  const float* c    = (const float*)d_in[2];
  const float* w_xf = (const float*)d_in[3];
  const float* w_hf = (const float*)d_in[4];
  const float* b_f  = (const float*)d_in[5];
  const float* w_xi = (const float*)d_in[6];
  const float* w_hi = (const float*)d_in[7];
  const float* b_i  = (const float*)d_in[8];
  const float* w_xo = (const float*)d_in[9];
  const float* w_ho = (const float*)d_in[10];
  const float* b_o  = (const float*)d_in[11];
  const float* w_xc = (const float*)d_in[12];
  const float* w_hc = (const float*)d_in[13];
  const float* b_c  = (const float*)d_in[14];

  float* hout  = (float*)d_out;
  float* cout_ = hout + (size_t)8192 * 2048;

  short* X2 = (short*)d_ws;                       // 64 MiB
  short* W3 = X2 + (size_t)8192 * 4096;           // 64 MiB

  const int packBlocks = (int)(((long)8192 * 4096 / 8) / 256);  // 16384
  pack_x_kernel<<<packBlocks, 256, 0, stream>>>(x, h, X2);
  pack_w_kernel<<<packBlocks, 256, 0, stream>>>(w_xf, w_xi, w_xo, w_xc,
                                                w_hf, w_hi, w_ho, w_hc, W3);

  lstm_fused_gemm<<<1024, 512, 0, stream>>>(X2, W3, c, b_f, b_i, b_o, b_c,
                                            hout, cout_);
}